// Round 5
// baseline (19745.705 us; speedup 1.0000x reference)
//
#include <hip/hip_runtime.h>
#include <hip/hip_cooperative_groups.h>
#include <math.h>

namespace cg = cooperative_groups;

namespace {

constexpr int Bn = 512;
constexpr int Ln = 100;
constexpr int En = 256;
constexpr int Hn = 256;
constexpr int Tn = 100;

// fast tanh: sign(x) * (1 - e^{-2|x|}) / (1 + e^{-2|x|});  ~3e-8 abs error
__device__ __forceinline__ float fast_tanh(float x) {
  float ax = fabsf(x);
  float e = __expf(-2.0f * ax);
  float t = (1.0f - e) / (1.0f + e);
  return copysignf(t, x);
}
__device__ __forceinline__ float fast_sigm(float x) {
  return 1.0f / (1.0f + __expf(-x));
}

__device__ __forceinline__ float wave_max(float v) {
#pragma unroll
  for (int off = 32; off > 0; off >>= 1) v = fmaxf(v, __shfl_xor(v, off, 64));
  return v;
}
__device__ __forceinline__ float wave_sum(float v) {
#pragma unroll
  for (int off = 32; off > 0; off >>= 1) v += __shfl_xor(v, off, 64);
  return v;
}

// ---------------------------------------------------------------- init
__global__ void init_kernel(const float* __restrict__ dec, const float* __restrict__ h0,
                            const float* __restrict__ c0, float* __restrict__ x,
                            float* __restrict__ h, float* __restrict__ c,
                            int* __restrict__ mask, int* __restrict__ prev) {
  int i = blockIdx.x * 256 + threadIdx.x;
  if (i < Bn * En) x[i] = dec[i];
  if (i < Bn * Hn) { h[i] = h0[i]; c[i] = c0[i]; }
  if (i < Bn * Ln) mask[i] = 0;
  if (i < Bn) prev[i] = 0;
}

// ------------------------------------------------------- 256x256 transpose
__global__ void transpose256_kernel(const float* __restrict__ W, float* __restrict__ WT) {
  int h = blockIdx.x, k = threadIdx.x;
  WT[k * 256 + h] = W[h * 256 + k];
}

// ----------------------------------------------- M = pWq @ gWref  (256x256)
__global__ void matmul_M_kernel(const float* __restrict__ pWq,
                                const float* __restrict__ gWref,
                                float* __restrict__ M) {
  int i = blockIdx.x, j = threadIdx.x;
  float acc = 0.0f;
  for (int h = 0; h < 256; ++h) acc += pWq[i * 256 + h] * gWref[h * 256 + j];
  M[i * 256 + j] = acc;
}

// ----------------------------------------------- mb = pWq @ gbref  (256)
__global__ void mb_kernel(const float* __restrict__ pWq,
                          const float* __restrict__ gbref,
                          float* __restrict__ mb) {
  __shared__ float gb[256];
  int i = threadIdx.x;
  gb[i] = gbref[i];
  __syncthreads();
  float acc = 0.0f;
  for (int h = 0; h < 256; ++h) acc += pWq[i * 256 + h] * gb[h];
  mb[i] = acc;
}

// ------------------------------------------------- e_t[b][l][h] = (W @ ctx)[b,h,l] + bref[h]
__global__ __launch_bounds__(256) void precompute_e_kernel(
    const float* __restrict__ WT, const float* __restrict__ bref,
    const float* __restrict__ context, float* __restrict__ e_t) {
  int b = blockIdx.x;           // 0..511
  int l0 = blockIdx.y * 25;     // 4 chunks of 25
  int h = threadIdx.x;          // 0..255
  __shared__ float ctx_s[25][256];
  for (int li = 0; li < 25; ++li)
    ctx_s[li][h] = context[((size_t)(l0 + li) * Bn + b) * Hn + h];
  __syncthreads();
  float acc[25];
  float bias = bref[h];
#pragma unroll
  for (int li = 0; li < 25; ++li) acc[li] = bias;
  for (int k = 0; k < 256; ++k) {
    float w = WT[k * 256 + h];
#pragma unroll
    for (int li = 0; li < 25; ++li) acc[li] += w * ctx_s[li][k];
  }
#pragma unroll
  for (int li = 0; li < 25; ++li)
    e_t[((size_t)b * Ln + (l0 + li)) * Hn + h] = acc[li];   // lanes h: coalesced
}

// =================================================================
// Persistent cooperative kernel: 256 blocks x 256 threads.
// Phase 1: gates[b][n] = x[b]@Wi[n] + h[b]@Wh[n] + bi[n] + bh[n], full K=512.
//   grid = (bt:8 x 64 batches) x (nt:32 x 32 cols); thread tile 4b x 2c.
// Phase 2: each block handles batches 2*blk, 2*blk+1 sequentially:
//   cell update, qp_g matvec, glimpse attn, f_p readout -> q2, pointer attn,
//   argmax, x-update.  (R3-validated attention body.)
// =================================================================
__global__ __launch_bounds__(256) void persistent_kernel(
    const float* __restrict__ Wi, const float* __restrict__ Wh,
    const float* __restrict__ bi, const float* __restrict__ bh,
    const float* __restrict__ WqTg, const float* __restrict__ gbq,
    const float* __restrict__ gv, const float* __restrict__ pv,
    const float* __restrict__ pbq, const float* __restrict__ e_g,
    const float* __restrict__ f_p, const float* __restrict__ e_p,
    float* __restrict__ gates, float* __restrict__ xbuf,
    float* __restrict__ hbuf, float* __restrict__ cbuf,
    int* __restrict__ mask, int* __restrict__ prev,
    const float* __restrict__ emb, float* __restrict__ out) {
  cg::grid_group grid = cg::this_grid();
  const int blk = blockIdx.x;
  const int tid = threadIdx.x;

  __shared__ union SM {
    struct { float A[64][36]; float W[32][36]; } l;   // 13.8 KB
    struct {
      float hs[256], q1[256], q2[256], vg[256], vp[256];
      float qtmp[4][256];
      float logit[128], p[128];
      float wred_m[2], wred_s[2], wval[2];
      int widx[2];
      int sel;
    } a;                                              // ~10.3 KB
  } sm;

  // phase-1 decode (constant across t)
  const int nt = blk & 31;          // 32 col-groups of 32
  const int bt = blk >> 5;          // 8 batch-groups of 64
  const int n0 = nt * 32;
  const int b0 = bt * 64;
  const int tx = tid & 15;          // 16 -> 4 batches each
  const int ty = tid >> 4;          // 16 -> 2 cols each
  // phase-2
  const int li = tid & 127;
  const int half = tid >> 7;
  const size_t hbase = (size_t)Tn * Bn * Ln + (size_t)Tn * Bn;
  const size_t cbase = hbase + (size_t)Bn * Hn;

  for (int t = 0; t < Tn; ++t) {
    // ================= Phase 1: LSTM gates (full K) =================
    float acc[4][2];
    {
      float bias0 = bi[n0 + 2 * ty] + bh[n0 + 2 * ty];
      float bias1 = bi[n0 + 2 * ty + 1] + bh[n0 + 2 * ty + 1];
#pragma unroll
      for (int i = 0; i < 4; ++i) { acc[i][0] = bias0; acc[i][1] = bias1; }
    }
    for (int kc = 0; kc < 16; ++kc) {
      const float* Asrc = (kc < 8) ? xbuf : hbuf;
      const float* Wsrc = (kc < 8) ? Wi : Wh;
      const int kb = (kc & 7) * 32;
      __syncthreads();
#pragma unroll
      for (int i = 0; i < 2; ++i) {
        int slot = tid + i * 256;       // 512 float4 slots = 64 rows x 8
        int row = slot >> 3, kq = slot & 7;
        float4 av = *(const float4*)(Asrc + (size_t)(b0 + row) * 256 + kb + kq * 4);
        *(float4*)&sm.l.A[row][kq * 4] = av;
      }
      {
        int row = tid >> 3, kq = tid & 7;  // 256 float4 slots = 32 rows x 8
        float4 wv = *(const float4*)(Wsrc + (size_t)(n0 + row) * 256 + kb + kq * 4);
        *(float4*)&sm.l.W[row][kq * 4] = wv;
      }
      __syncthreads();
#pragma unroll
      for (int kj = 0; kj < 8; ++kj) {
        float4 aa[4], ww[2];
#pragma unroll
        for (int i = 0; i < 4; ++i) aa[i] = *(const float4*)&sm.l.A[4 * tx + i][4 * kj];
#pragma unroll
        for (int j = 0; j < 2; ++j) ww[j] = *(const float4*)&sm.l.W[2 * ty + j][4 * kj];
#pragma unroll
        for (int i = 0; i < 4; ++i)
#pragma unroll
          for (int j = 0; j < 2; ++j)
            acc[i][j] += aa[i].x * ww[j].x + aa[i].y * ww[j].y +
                         aa[i].z * ww[j].z + aa[i].w * ww[j].w;
      }
    }
#pragma unroll
    for (int i = 0; i < 4; ++i) {
      float2 st = make_float2(acc[i][0], acc[i][1]);
      *(float2*)&gates[(size_t)(b0 + 4 * tx + i) * 1024 + n0 + 2 * ty] = st;
    }
    grid.sync();

    // ================= Phase 2: two batches per block =================
    for (int b2 = 0; b2 < 2; ++b2) {
      const int b = 2 * blk + b2;
      // ---- cell update (h-index = tid)
      {
        float g4[4];
#pragma unroll
        for (int g = 0; g < 4; ++g) g4[g] = gates[(size_t)b * 1024 + g * 256 + tid];
        float cold = cbuf[b * 256 + tid];
        float cy = fast_sigm(g4[1]) * cold + fast_sigm(g4[0]) * fast_tanh(g4[2]);
        float hy = fast_sigm(g4[3]) * fast_tanh(cy);
        cbuf[b * 256 + tid] = cy;
        hbuf[b * 256 + tid] = hy;
        sm.a.hs[tid] = hy;
        if (t == Tn - 1) {
          out[hbase + b * 256 + tid] = hy;
          out[cbase + b * 256 + tid] = cy;
        }
      }
      __syncthreads();
      // ---- qp_g[h'] = gbq[h'] + sum_k h[k] * WqTg[k][h']   (K-split 4)
      {
        int ks = tid >> 6, ho = tid & 63;
        float ax = 0, ay = 0, az = 0, aw = 0;
        const float* wb = WqTg + (size_t)ks * 64 * 256 + 4 * ho;
#pragma unroll 8
        for (int k = 0; k < 64; ++k) {
          float hk = sm.a.hs[ks * 64 + k];
          float4 w = *(const float4*)(wb + (size_t)k * 256);
          ax += hk * w.x; ay += hk * w.y; az += hk * w.z; aw += hk * w.w;
        }
        sm.a.qtmp[ks][4 * ho + 0] = ax;
        sm.a.qtmp[ks][4 * ho + 1] = ay;
        sm.a.qtmp[ks][4 * ho + 2] = az;
        sm.a.qtmp[ks][4 * ho + 3] = aw;
      }
      __syncthreads();
      sm.a.q1[tid] = gbq[tid] + sm.a.qtmp[0][tid] + sm.a.qtmp[1][tid] +
                     sm.a.qtmp[2][tid] + sm.a.qtmp[3][tid];
      sm.a.vg[tid] = gv[tid];
      sm.a.vp[tid] = pv[tid];
      __syncthreads();
      // ---- glimpse logits
      float part = 0.0f;
      if (li < Ln) {
        const float4* ep = (const float4*)(e_g + ((size_t)b * Ln + li) * Hn + half * 128);
        const float4* q4 = (const float4*)(sm.a.q1 + half * 128);
        const float4* v4 = (const float4*)(sm.a.vg + half * 128);
#pragma unroll 8
        for (int j = 0; j < 32; ++j) {
          float4 ev = ep[j];
          float4 qv = q4[j];
          float4 vv = v4[j];
          part += vv.x * fast_tanh(qv.x + ev.x);
          part += vv.y * fast_tanh(qv.y + ev.y);
          part += vv.z * fast_tanh(qv.z + ev.z);
          part += vv.w * fast_tanh(qv.w + ev.w);
        }
      }
      if (half == 1) sm.a.logit[li] = part;
      __syncthreads();
      float lgv = -INFINITY;
      int mreg = 1;
      if (half == 0 && li < Ln) {
        float a = part + sm.a.logit[li];
        int pb = prev[b];
        int m = mask[b * Ln + li];
        if (t == 0) {
          if (li == 0) m = 1;
        } else {
          if (t == 1 && li == 0) m = 0;
          if (li == pb) m = 1;
        }
        mask[b * Ln + li] = m;  // single update/step; pointer-phase apply_mask idempotent
        mreg = m;
        lgv = m ? -INFINITY : a;
      }
      // ---- glimpse softmax -> p
      float wm = wave_max((tid < 128) ? lgv : -INFINITY);
      if (tid < 128 && (tid & 63) == 0) sm.a.wred_m[tid >> 6] = wm;
      __syncthreads();
      float mx = fmaxf(sm.a.wred_m[0], sm.a.wred_m[1]);
      float pvv = (lgv == -INFINITY) ? 0.0f : __expf(lgv - mx);
      float wsm = wave_sum((tid < 128) ? pvv : 0.0f);
      if (tid < 128 && (tid & 63) == 0) sm.a.wred_s[tid >> 6] = wsm;
      __syncthreads();
      float tot = sm.a.wred_s[0] + sm.a.wred_s[1];
      if (tid < 128) sm.a.p[li] = pvv / tot;   // 0 for li >= Ln
      __syncthreads();
      // ---- q2[h'] = pbq[h'] + sum_l p[l] * f_p[b,l,h']
      {
        float accq = pbq[tid];
        const float* fb = f_p + (size_t)b * Ln * Hn + tid;
#pragma unroll 4
        for (int l = 0; l < Ln; ++l) accq += sm.a.p[l] * fb[(size_t)l * Hn];
        sm.a.q2[tid] = accq;
      }
      __syncthreads();
      // ---- pointer logits
      part = 0.0f;
      if (li < Ln) {
        const float4* ep = (const float4*)(e_p + ((size_t)b * Ln + li) * Hn + half * 128);
        const float4* q4 = (const float4*)(sm.a.q2 + half * 128);
        const float4* v4 = (const float4*)(sm.a.vp + half * 128);
#pragma unroll 8
        for (int j = 0; j < 32; ++j) {
          float4 ev = ep[j];
          float4 qv = q4[j];
          float4 vv = v4[j];
          part += vv.x * fast_tanh(qv.x + ev.x);
          part += vv.y * fast_tanh(qv.y + ev.y);
          part += vv.z * fast_tanh(qv.z + ev.z);
          part += vv.w * fast_tanh(qv.w + ev.w);
        }
      }
      if (half == 1) sm.a.logit[li] = part;
      __syncthreads();
      lgv = -INFINITY;
      if (half == 0 && li < Ln) {
        float a = part + sm.a.logit[li];
        float lp = 10.0f * fast_tanh(a);
        lgv = mreg ? -INFINITY : lp;
      }
      // ---- pointer softmax + probs + argmax
      wm = wave_max((tid < 128) ? lgv : -INFINITY);
      if (tid < 128 && (tid & 63) == 0) sm.a.wred_m[tid >> 6] = wm;
      __syncthreads();
      mx = fmaxf(sm.a.wred_m[0], sm.a.wred_m[1]);
      pvv = (lgv == -INFINITY) ? 0.0f : __expf(lgv - mx);
      wsm = wave_sum((tid < 128) ? pvv : 0.0f);
      if (tid < 128 && (tid & 63) == 0) sm.a.wred_s[tid >> 6] = wsm;
      __syncthreads();
      tot = sm.a.wred_s[0] + sm.a.wred_s[1];
      float p = pvv / tot;
      if (half == 0 && li < Ln) out[((size_t)t * Bn + b) * Ln + li] = p;
      float val = (tid < 128 && li < Ln) ? p : -1.0f;
      int idx = li;
#pragma unroll
      for (int off = 32; off > 0; off >>= 1) {
        float ov = __shfl_down(val, off, 64);
        int oi = __shfl_down(idx, off, 64);
        if (ov > val || (ov == val && oi < idx)) { val = ov; idx = oi; }
      }
      if (tid < 128 && (tid & 63) == 0) { sm.a.wval[tid >> 6] = val; sm.a.widx[tid >> 6] = idx; }
      __syncthreads();
      if (tid == 0) {
        int sel = (sm.a.wval[1] > sm.a.wval[0] ||
                   (sm.a.wval[1] == sm.a.wval[0] && sm.a.widx[1] < sm.a.widx[0]))
                      ? sm.a.widx[1] : sm.a.widx[0];
        sm.a.sel = sel;
        prev[b] = sel;
        out[(size_t)Tn * Bn * Ln + (size_t)t * Bn + b] = (float)sel;
      }
      __syncthreads();
      {
        int sel = sm.a.sel;
        xbuf[b * 256 + tid] = emb[((size_t)sel * Bn + b) * En + tid];
      }
      __syncthreads();   // sm.a reused by next b2
    }
    grid.sync();
  }
}

// =================================================================
// R3-validated fallback kernels (used only if cooperative launch fails)
// =================================================================
__global__ __launch_bounds__(256) void lstm_kernel(
    const float* __restrict__ x, const float* __restrict__ h_in,
    const float* __restrict__ c_in, const float* __restrict__ Wi,
    const float* __restrict__ Wh, const float* __restrict__ bi,
    const float* __restrict__ bh, float* __restrict__ h_out,
    float* __restrict__ c_out) {
  const int b0 = blockIdx.x * 32;
  const int n0 = blockIdx.y * 16;
  const int tid = threadIdx.x;
  const int n = tid & 15;
  const int br = tid >> 4;
  __shared__ float A_s[32][33];
  __shared__ float W_s[4][16][33];
  float acc[4][2];
  const int nn = n0 + n;
#pragma unroll
  for (int g = 0; g < 4; ++g) {
    float bias = bi[g * 256 + nn] + bh[g * 256 + nn];
    acc[g][0] = bias;
    acc[g][1] = bias;
  }
  const int bb = tid >> 3, q = tid & 7;
  for (int k0 = 0; k0 < 512; k0 += 32) {
    const float* Asrc = (k0 < 256) ? x : h_in;
    const float* Wsrc = (k0 < 256) ? Wi : Wh;
    const int kb = k0 & 255;
    __syncthreads();
    float4 av = *(const float4*)(Asrc + (b0 + bb) * 256 + kb + q * 4);
    A_s[q * 4 + 0][bb] = av.x;
    A_s[q * 4 + 1][bb] = av.y;
    A_s[q * 4 + 2][bb] = av.z;
    A_s[q * 4 + 3][bb] = av.w;
#pragma unroll
    for (int s = 0; s < 2; ++s) {
      int sl = tid + s * 256;
      int g = sl >> 7;
      int nl = (sl >> 3) & 15;
      int qq = sl & 7;
      float4 wv = *(const float4*)(Wsrc + ((g * 256 + n0 + nl) * 256) + kb + qq * 4);
      W_s[g][nl][qq * 4 + 0] = wv.x;
      W_s[g][nl][qq * 4 + 1] = wv.y;
      W_s[g][nl][qq * 4 + 2] = wv.z;
      W_s[g][nl][qq * 4 + 3] = wv.w;
    }
    __syncthreads();
#pragma unroll
    for (int kk = 0; kk < 32; ++kk) {
      float a0 = A_s[kk][2 * br];
      float a1 = A_s[kk][2 * br + 1];
#pragma unroll
      for (int g = 0; g < 4; ++g) {
        float w = W_s[g][n][kk];
        acc[g][0] += a0 * w;
        acc[g][1] += a1 * w;
      }
    }
  }
#pragma unroll
  for (int m = 0; m < 2; ++m) {
    int b = b0 + 2 * br + m;
    float ig = acc[0][m], fg = acc[1][m], cg = acc[2][m], og = acc[3][m];
    float cold = c_in[b * 256 + nn];
    float cy = fast_sigm(fg) * cold + fast_sigm(ig) * fast_tanh(cg);
    float hy = fast_sigm(og) * fast_tanh(cy);
    c_out[b * 256 + nn] = cy;
    h_out[b * 256 + nn] = hy;
  }
}

__global__ __launch_bounds__(256) void qp_gemm_kernel(
    const float* __restrict__ A, const float* __restrict__ Wq,
    const float* __restrict__ bq, float* __restrict__ C) {
  const int b0 = blockIdx.x * 32;
  const int n0 = blockIdx.y * 16;
  const int tid = threadIdx.x;
  const int n = tid & 15;
  const int br = tid >> 4;
  __shared__ float A_s[32][33];
  __shared__ float W_s[16][33];
  float bias = bq[n0 + n];
  float acc0 = bias, acc1 = bias;
  const int bb = tid >> 3, q = tid & 7;
  for (int k0 = 0; k0 < 256; k0 += 32) {
    __syncthreads();
    float4 av = *(const float4*)(A + (b0 + bb) * 256 + k0 + q * 4);
    A_s[q * 4 + 0][bb] = av.x;
    A_s[q * 4 + 1][bb] = av.y;
    A_s[q * 4 + 2][bb] = av.z;
    A_s[q * 4 + 3][bb] = av.w;
    if (tid < 128) {
      int nl = tid >> 3, qq = tid & 7;
      float4 wv = *(const float4*)(Wq + (n0 + nl) * 256 + k0 + qq * 4);
      W_s[nl][qq * 4 + 0] = wv.x;
      W_s[nl][qq * 4 + 1] = wv.y;
      W_s[nl][qq * 4 + 2] = wv.z;
      W_s[nl][qq * 4 + 3] = wv.w;
    }
    __syncthreads();
#pragma unroll
    for (int kk = 0; kk < 32; ++kk) {
      float a0 = A_s[kk][2 * br];
      float a1 = A_s[kk][2 * br + 1];
      float w = W_s[n][kk];
      acc0 += a0 * w;
      acc1 += a1 * w;
    }
  }
  C[(b0 + 2 * br) * 256 + n0 + n] = acc0;
  C[(b0 + 2 * br + 1) * 256 + n0 + n] = acc1;
}

__global__ __launch_bounds__(256) void attn_fused_kernel(
    const float* __restrict__ qp_g, const float* __restrict__ gv,
    const float* __restrict__ pv, const float* __restrict__ pbq,
    const float* __restrict__ e_g, const float* __restrict__ f_p,
    const float* __restrict__ e_p, int* __restrict__ mask,
    int* __restrict__ prev, const float* __restrict__ emb,
    float* __restrict__ xout, float* __restrict__ out, int step) {
  const int tid = threadIdx.x;
  const int b = blockIdx.x;
  const int li = tid & 127;
  const int half = tid >> 7;
  __shared__ float q1_s[256], vg_s[256], vp_s[256], q2_s[256];
  __shared__ float logit_s[128], p_s[128];
  __shared__ float wred_m[2], wred_s[2];
  __shared__ float wval[2];
  __shared__ int widx[2];
  __shared__ int sel_s;
  q1_s[tid] = qp_g[b * 256 + tid];
  vg_s[tid] = gv[tid];
  vp_s[tid] = pv[tid];
  __syncthreads();
  float part = 0.0f;
  if (li < Ln) {
    const float4* ep = (const float4*)(e_g + ((size_t)b * Ln + li) * Hn + half * 128);
    const float4* q4 = (const float4*)(q1_s + half * 128);
    const float4* v4 = (const float4*)(vg_s + half * 128);
#pragma unroll 8
    for (int j = 0; j < 32; ++j) {
      float4 ev = ep[j];
      float4 qv = q4[j];
      float4 vv = v4[j];
      part += vv.x * fast_tanh(qv.x + ev.x);
      part += vv.y * fast_tanh(qv.y + ev.y);
      part += vv.z * fast_tanh(qv.z + ev.z);
      part += vv.w * fast_tanh(qv.w + ev.w);
    }
  }
  if (half == 1) logit_s[li] = part;
  __syncthreads();
  float lgv = -INFINITY;
  int mreg = 1;
  if (half == 0 && li < Ln) {
    float a = part + logit_s[li];
    int pb = prev[b];
    int m = mask[b * Ln + li];
    if (step == 0) {
      if (li == 0) m = 1;
    } else {
      if (step == 1 && li == 0) m = 0;
      if (li == pb) m = 1;
    }
    mask[b * Ln + li] = m;
    mreg = m;
    lgv = m ? -INFINITY : a;
  }
  float wm = wave_max((tid < 128) ? lgv : -INFINITY);
  if (tid < 128 && (tid & 63) == 0) wred_m[tid >> 6] = wm;
  __syncthreads();
  float mx = fmaxf(wred_m[0], wred_m[1]);
  float pvv = (lgv == -INFINITY) ? 0.0f : __expf(lgv - mx);
  float wsm = wave_sum((tid < 128) ? pvv : 0.0f);
  if (tid < 128 && (tid & 63) == 0) wred_s[tid >> 6] = wsm;
  __syncthreads();
  float tot = wred_s[0] + wred_s[1];
  if (tid < 128) p_s[li] = pvv / tot;
  __syncthreads();
  {
    float acc = pbq[tid];
    const float* fb = f_p + (size_t)b * Ln * Hn + tid;
#pragma unroll 4
    for (int l = 0; l < Ln; ++l) acc += p_s[l] * fb[(size_t)l * Hn];
    q2_s[tid] = acc;
  }
  __syncthreads();
  part = 0.0f;
  if (li < Ln) {
    const float4* ep = (const float4*)(e_p + ((size_t)b * Ln + li) * Hn + half * 128);
    const float4* q4 = (const float4*)(q2_s + half * 128);
    const float4* v4 = (const float4*)(vp_s + half * 128);
#pragma unroll 8
    for (int j = 0; j < 32; ++j) {
      float4 ev = ep[j];
      float4 qv = q4[j];
      float4 vv = v4[j];
      part += vv.x * fast_tanh(qv.x + ev.x);
      part += vv.y * fast_tanh(qv.y + ev.y);
      part += vv.z * fast_tanh(qv.z + ev.z);
      part += vv.w * fast_tanh(qv.w + ev.w);
    }
  }
  if (half == 1) logit_s[li] = part;
  __syncthreads();
  lgv = -INFINITY;
  if (half == 0 && li < Ln) {
    float a = part + logit_s[li];
    float lp = 10.0f * fast_tanh(a);
    lgv = mreg ? -INFINITY : lp;
  }
  wm = wave_max((tid < 128) ? lgv : -INFINITY);
  if (tid < 128 && (tid & 63) == 0) wred_m[tid >> 6] = wm;
  __syncthreads();
  mx = fmaxf(wred_m[0], wred_m[1]);
  pvv = (lgv == -INFINITY) ? 0.0f : __expf(lgv - mx);
  wsm = wave_sum((tid < 128) ? pvv : 0.0f);
  if (tid < 128 && (tid & 63) == 0) wred_s[tid >> 6] = wsm;
  __syncthreads();
  tot = wred_s[0] + wred_s[1];
  float p = pvv / tot;
  if (half == 0 && li < Ln) out[((size_t)step * Bn + b) * Ln + li] = p;
  float val = (tid < 128 && li < Ln) ? p : -1.0f;
  int idx = li;
#pragma unroll
  for (int off = 32; off > 0; off >>= 1) {
    float ov = __shfl_down(val, off, 64);
    int oi = __shfl_down(idx, off, 64);
    if (ov > val || (ov == val && oi < idx)) { val = ov; idx = oi; }
  }
  if (tid < 128 && (tid & 63) == 0) { wval[tid >> 6] = val; widx[tid >> 6] = idx; }
  __syncthreads();
  if (tid == 0) {
    int sel = (wval[1] > wval[0] || (wval[1] == wval[0] && widx[1] < widx[0]))
                  ? widx[1] : widx[0];
    sel_s = sel;
    prev[b] = sel;
    out[(size_t)Tn * Bn * Ln + (size_t)step * Bn + b] = (float)sel;
  }
  __syncthreads();
  int sel = sel_s;
  xout[b * En + tid] = emb[((size_t)sel * Bn + b) * En + tid];
}

__global__ void finalize_kernel(const float* __restrict__ h,
                                const float* __restrict__ c,
                                float* __restrict__ out) {
  int i = blockIdx.x * 256 + threadIdx.x;
  const size_t base = (size_t)Tn * Bn * Ln + (size_t)Tn * Bn;
  if (i < Bn * Hn) {
    out[base + i] = h[i];
    out[base + (size_t)Bn * Hn + i] = c[i];
  }
}

}  // namespace

extern "C" void kernel_launch(void* const* d_in, const int* in_sizes, int n_in,
                              void* d_out, int out_size, void* d_ws, size_t ws_size,
                              hipStream_t stream) {
  (void)in_sizes; (void)n_in; (void)out_size; (void)ws_size;
  const float* dec   = (const float*)d_in[0];
  const float* emb   = (const float*)d_in[1];
  const float* h0    = (const float*)d_in[2];
  const float* c0    = (const float*)d_in[3];
  const float* ctx   = (const float*)d_in[4];
  const float* Wi    = (const float*)d_in[5];
  const float* bi    = (const float*)d_in[6];
  const float* Wh    = (const float*)d_in[7];
  const float* bh    = (const float*)d_in[8];
  const float* gWq   = (const float*)d_in[9];
  const float* gbq   = (const float*)d_in[10];
  const float* gWref = (const float*)d_in[11];
  const float* gbref = (const float*)d_in[12];
  const float* gv    = (const float*)d_in[13];
  const float* pWq   = (const float*)d_in[14];
  const float* pbq   = (const float*)d_in[15];
  const float* pWref = (const float*)d_in[16];
  const float* pbref = (const float*)d_in[17];
  const float* pv    = (const float*)d_in[18];

  float* ws = (float*)d_ws;
  float* e_g   = ws;  ws += (size_t)Bn * Hn * Ln;   // [b][l][h]
  float* e_p   = ws;  ws += (size_t)Bn * Hn * Ln;   // [b][l][h]
  float* f_p   = ws;  ws += (size_t)Bn * Hn * Ln;   // [b][l][h']
  float* WTg   = ws;  ws += 256 * 256;
  float* WTp   = ws;  ws += 256 * 256;
  float* Mbuf  = ws;  ws += 256 * 256;
  float* MT    = ws;  ws += 256 * 256;
  float* WqTg  = ws;  ws += 256 * 256;
  float* mb    = ws;  ws += 256;
  float* gates = ws;  ws += (size_t)Bn * 1024;
  float* xbuf  = ws;  ws += Bn * En;
  float* hbuf  = ws;  ws += 2 * Bn * Hn;   // persistent path uses first half
  float* cbuf  = ws;  ws += 2 * Bn * Hn;
  float* qpg   = ws;  ws += Bn * Hn;       // fallback only
  int* maskb   = (int*)ws;  ws += Bn * Ln;
  int* prevb   = (int*)ws;  ws += Bn;
  float* out = (float*)d_out;

  init_kernel<<<512, 256, 0, stream>>>(dec, h0, c0, xbuf, hbuf, cbuf, maskb, prevb);
  transpose256_kernel<<<256, 256, 0, stream>>>(gWref, WTg);
  transpose256_kernel<<<256, 256, 0, stream>>>(pWref, WTp);
  transpose256_kernel<<<256, 256, 0, stream>>>(gWq, WqTg);
  matmul_M_kernel<<<256, 256, 0, stream>>>(pWq, gWref, Mbuf);
  mb_kernel<<<1, 256, 0, stream>>>(pWq, gbref, mb);
  transpose256_kernel<<<256, 256, 0, stream>>>(Mbuf, MT);
  precompute_e_kernel<<<dim3(512, 4), 256, 0, stream>>>(WTg, gbref, ctx, e_g);
  precompute_e_kernel<<<dim3(512, 4), 256, 0, stream>>>(WTp, pbref, ctx, e_p);
  precompute_e_kernel<<<dim3(512, 4), 256, 0, stream>>>(MT, mb, ctx, f_p);

  void* args[] = {
      (void*)&Wi, (void*)&Wh, (void*)&bi, (void*)&bh,
      (void*)&WqTg, (void*)&gbq, (void*)&gv, (void*)&pv,
      (void*)&pbq, (void*)&e_g, (void*)&f_p, (void*)&e_p,
      (void*)&gates, (void*)&xbuf, (void*)&hbuf, (void*)&cbuf,
      (void*)&maskb, (void*)&prevb, (void*)&emb, (void*)&out};
  hipError_t st = hipLaunchCooperativeKernel((const void*)persistent_kernel,
                                             dim3(256), dim3(256), args, 0, stream);
  if (st != hipSuccess) {
    // Deterministic fallback: R3-validated per-step kernels.
    for (int t = 0; t < Tn; ++t) {
      const float* hin = hbuf + (t & 1) * Bn * Hn;
      float* hout      = hbuf + ((t + 1) & 1) * Bn * Hn;
      const float* cin = cbuf + (t & 1) * Bn * Hn;
      float* cout      = cbuf + ((t + 1) & 1) * Bn * Hn;
      lstm_kernel<<<dim3(16, 16), 256, 0, stream>>>(xbuf, hin, cin, Wi, Wh, bi, bh, hout, cout);
      qp_gemm_kernel<<<dim3(16, 16), 256, 0, stream>>>(hout, gWq, gbq, qpg);
      attn_fused_kernel<<<512, 256, 0, stream>>>(qpg, gv, pv, pbq, e_g, f_p, e_p,
                                                 maskb, prevb, emb, xbuf, out, t);
    }
    finalize_kernel<<<512, 256, 0, stream>>>(hbuf, cbuf, out);
  }
}